// Round 10
// baseline (9152.045 us; speedup 1.0000x reference)
//
#include <hip/hip_runtime.h>

typedef float f32x4 __attribute__((ext_vector_type(4)));

// ===========================================================================
// Round 10: full-f32 VALU pipeline (no MFMA, no bf16 anywhere).
// Theory: inputs AND output are float32 (reference is pure-f32 JAX).
// All previous rounds wrote bf16 into an f32-read buffer -> deterministic
// scramble -> frozen absmax 0.4404. This round is the correctness anchor.
// Batch-split (b=0,1 sequential launches) so ws fits in 32 MB (<51 MB known).
// ===========================================================================

// ---------------------------------------------------------------------------
// Naive row-GEMM, f32: C[row][col] = A[row] . W[col][:] (+bias)
// A: [4096 x 512] (one batch), W: [512 x 512] row-major [out][in].
// One block per row; thread t computes cols t and t+256.
// A-row loads are wave-uniform (broadcast); W rows are L2-resident (1 MB).
// ---------------------------------------------------------------------------
__device__ __forceinline__ void p10_row_gemm(const float* __restrict__ A,
                                             const float* __restrict__ W,
                                             const float* __restrict__ bias,
                                             float* __restrict__ out)
{
    const int row = blockIdx.x;
    const float* ap = A + (size_t)row * 512;
#pragma unroll
    for (int cc = 0; cc < 2; cc++) {
        const int col = threadIdx.x + cc * 256;
        const float* wp = W + (size_t)col * 512;
        float acc = 0.f;
        for (int k4 = 0; k4 < 128; k4++) {
            f32x4 a4 = *(const f32x4*)(ap + k4 * 4);
            f32x4 w4 = *(const f32x4*)(wp + k4 * 4);
#pragma unroll
            for (int j = 0; j < 4; j++) acc += a4[j] * w4[j];
        }
        if (bias) acc += bias[col];
        out[(size_t)row * 512 + col] = acc;
    }
}

__global__ __launch_bounds__(256) void p10_qkv(
    const float* __restrict__ xb,  const float* __restrict__ ctxb,
    const float* __restrict__ wq,  const float* __restrict__ wk,
    const float* __restrict__ wv,
    float* __restrict__ Qb, float* __restrict__ Kb, float* __restrict__ Vb)
{
    if (blockIdx.z == 0)      p10_row_gemm(xb,   wq, nullptr, Qb);
    else if (blockIdx.z == 1) p10_row_gemm(ctxb, wk, nullptr, Kb);
    else                      p10_row_gemm(ctxb, wv, nullptr, Vb);
}

__global__ __launch_bounds__(256) void p10_oproj(
    const float* __restrict__ Ob, const float* __restrict__ wout,
    const float* __restrict__ bout, float* __restrict__ outb)
{
    p10_row_gemm(Ob, wout, bout, outb);
}

// ---------------------------------------------------------------------------
// Naive attention, f32, one batch: one thread per (h,s) pair-of-grid;
// online softmax over all 4096 context positions. All 64 lanes of a wave
// share (h) and the c-loop -> K/V row loads are wave-uniform (broadcast).
// ---------------------------------------------------------------------------
__global__ __launch_bounds__(256) void p10_attn(
    const float* __restrict__ Qb, const float* __restrict__ Kb,
    const float* __restrict__ Vb, float* __restrict__ Ob)
{
    const int h = blockIdx.y;
    const int s = blockIdx.x * 256 + threadIdx.x;

    const float* qp = Qb + (size_t)s * 512 + h * 64;
    float q[64];
#pragma unroll
    for (int j = 0; j < 64; j++) q[j] = qp[j] * 0.125f;   // SCALE = 64^-0.5

    float o[64];
#pragma unroll
    for (int j = 0; j < 64; j++) o[j] = 0.f;
    float m = -3.4e38f, l = 0.f;

    const float* Kg = Kb + h * 64;
    const float* Vg = Vb + h * 64;

    for (int c = 0; c < 4096; c++) {
        const float* kp = Kg + (size_t)c * 512;
        float sv = 0.f;
#pragma unroll
        for (int j4 = 0; j4 < 16; j4++) {
            f32x4 k4 = *(const f32x4*)(kp + j4 * 4);
#pragma unroll
            for (int j = 0; j < 4; j++) sv += q[j4 * 4 + j] * k4[j];
        }
        const float mn = fmaxf(m, sv);
        const float al = __expf(m - mn);
        const float p  = __expf(sv - mn);
        l = l * al + p;
        m = mn;
        const float* vp = Vg + (size_t)c * 512;
#pragma unroll
        for (int j4 = 0; j4 < 16; j4++) {
            f32x4 v4 = *(const f32x4*)(vp + j4 * 4);
#pragma unroll
            for (int j = 0; j < 4; j++)
                o[j4 * 4 + j] = o[j4 * 4 + j] * al + p * v4[j];
        }
    }

    const float rl = 1.0f / l;
    float* op = Ob + (size_t)s * 512 + h * 64;
#pragma unroll
    for (int j = 0; j < 64; j++) op[j] = o[j] * rl;
}

// ws-too-small signature, now written as f32 (visible): absmax ~777
__global__ void p10_wssig(float* out) { if (threadIdx.x == 0) out[0] = 777.0f; }

// ---------------------------------------------------------------------------
extern "C" void kernel_launch(void* const* d_in, const int* in_sizes, int n_in,
                              void* d_out, int out_size, void* d_ws, size_t ws_size,
                              hipStream_t stream)
{
    // Inputs in setup_inputs() dict order, all float32:
    const float* x    = (const float*)d_in[0];   // [2,4096,512]
    const float* ctx  = (const float*)d_in[1];   // [2,4096,512]
    const float* wq   = (const float*)d_in[2];   // [512,512]
    const float* wk   = (const float*)d_in[3];
    const float* wv   = (const float*)d_in[4];
    const float* wout = (const float*)d_in[5];
    const float* bout = (const float*)d_in[6];   // [512]
    float* out = (float*)d_out;                  // [2,4096,512] float32

    char* ws = (char*)d_ws;
    const size_t MB = 1024 * 1024;
    const size_t SB = (size_t)4096 * 512 * sizeof(float);  // 8 MiB per-batch buf
    if (ws_size < 33 * MB) {
        p10_wssig<<<dim3(1), dim3(64), 0, stream>>>(out);
        return;
    }

    float* Qb = (float*)(ws);
    float* Kb = (float*)(ws + SB);
    float* Vb = (float*)(ws + 2 * SB);
    float* Ob = (float*)(ws + 3 * SB);

    for (int b = 0; b < 2; b++) {
        const float* xb   = x   + (size_t)b * 4096 * 512;
        const float* ctxb = ctx + (size_t)b * 4096 * 512;
        float* outb = out + (size_t)b * 4096 * 512;

        p10_qkv<<<dim3(4096, 1, 3), dim3(256), 0, stream>>>(
            xb, ctxb, wq, wk, wv, Qb, Kb, Vb);
        p10_attn<<<dim3(16, 8, 1), dim3(256), 0, stream>>>(Qb, Kb, Vb, Ob);
        p10_oproj<<<dim3(4096, 1, 1), dim3(256), 0, stream>>>(Ob, wout, bout, outb);
    }
}

// Round 11
// 363.541 us; speedup vs baseline: 25.1747x; 25.1747x over previous
//
#include <hip/hip_runtime.h>

typedef __bf16 bf16;
typedef __bf16 bf16x8 __attribute__((ext_vector_type(8)));
typedef float  f32x4  __attribute__((ext_vector_type(4)));

#define MFMA16(a,b,c) __builtin_amdgcn_mfma_f32_16x16x32_bf16(a,b,c,0,0,0)

// Load 8 consecutive f32 and round to bf16x8 (for LDS staging).
__device__ __forceinline__ bf16x8 ld8_f32_to_bf16(const float* __restrict__ p)
{
    f32x4 a = *(const f32x4*)p;
    f32x4 b = *(const f32x4*)(p + 4);
    bf16x8 o;
#pragma unroll
    for (int j = 0; j < 4; j++) { o[j] = (bf16)a[j]; o[4 + j] = (bf16)b[j]; }
    return o;
}

// ---------------------------------------------------------------------------
// QKV GEMM (m97-style, 16x16x32): C[8192x512] = A[8192x512] @ W[512x512]^T.
// A,W are f32 in HBM, converted to bf16 during LDS staging.
// mode 0: bf16 store out[row*512+col]
// mode 1: V^T bf16 store out[((b*8+h)*64+d)*4096 + c]
// Verified layouts: A-frag[m=lane&15][k=quad*8+j], B-frag[n=lane&15][k],
// C/D col=lane&15, row=quad*4+reg.
// ---------------------------------------------------------------------------
__global__ __launch_bounds__(256, 2) void mm_qkv(
    const float* __restrict__ x,  const float* __restrict__ ctx,
    const float* __restrict__ wq, const float* __restrict__ wk,
    const float* __restrict__ wv,
    bf16* __restrict__ Qb, bf16* __restrict__ Kb, bf16* __restrict__ Vtb)
{
    __shared__ bf16 Al[128 * 40];
    __shared__ bf16 Wl[128 * 40];

    const float* A; const float* W; bf16* out; int mode;
    if (blockIdx.z == 0)      { A = x;   W = wq; out = Qb;  mode = 0; }
    else if (blockIdx.z == 1) { A = ctx; W = wk; out = Kb;  mode = 0; }
    else                      { A = ctx; W = wv; out = Vtb; mode = 1; }

    const int tid  = threadIdx.x;
    const int lane = tid & 63;
    const int w    = tid >> 6;
    const int wr   = w >> 1, wc = w & 1;
    const int bx   = blockIdx.x, by = blockIdx.y;
    const int q    = lane >> 4, m0 = lane & 15;

    f32x4 acc[4][4];
#pragma unroll
    for (int i = 0; i < 4; i++)
#pragma unroll
        for (int j = 0; j < 4; j++)
#pragma unroll
            for (int r = 0; r < 4; r++) acc[i][j][r] = 0.f;

    const int r0 = tid >> 2;
    const int c0 = (tid & 3) * 8;
    const float* Ab = A + (size_t)(by * 128) * 512;
    const float* Wb = W + (size_t)(bx * 128) * 512;

    for (int k0 = 0; k0 < 512; k0 += 32) {
        *(bf16x8*)&Al[r0 * 40 + c0]        = ld8_f32_to_bf16(Ab + (size_t)r0 * 512 + k0 + c0);
        *(bf16x8*)&Al[(r0 + 64) * 40 + c0] = ld8_f32_to_bf16(Ab + (size_t)(r0 + 64) * 512 + k0 + c0);
        *(bf16x8*)&Wl[r0 * 40 + c0]        = ld8_f32_to_bf16(Wb + (size_t)r0 * 512 + k0 + c0);
        *(bf16x8*)&Wl[(r0 + 64) * 40 + c0] = ld8_f32_to_bf16(Wb + (size_t)(r0 + 64) * 512 + k0 + c0);
        __syncthreads();

        bf16x8 af[4], wf[4];
#pragma unroll
        for (int mt = 0; mt < 4; mt++)
            af[mt] = *(const bf16x8*)&Al[(wr * 64 + mt * 16 + m0) * 40 + q * 8];
#pragma unroll
        for (int nt = 0; nt < 4; nt++)
            wf[nt] = *(const bf16x8*)&Wl[(wc * 64 + nt * 16 + m0) * 40 + q * 8];
#pragma unroll
        for (int mt = 0; mt < 4; mt++)
#pragma unroll
            for (int nt = 0; nt < 4; nt++)
                acc[mt][nt] = MFMA16(af[mt], wf[nt], acc[mt][nt]);
        __syncthreads();
    }

#pragma unroll
    for (int nt = 0; nt < 4; nt++) {
        const int col = bx * 128 + wc * 64 + nt * 16 + m0;
#pragma unroll
        for (int mt = 0; mt < 4; mt++) {
#pragma unroll
            for (int r = 0; r < 4; r++) {
                const int row = by * 128 + wr * 64 + mt * 16 + q * 4 + r;
                const bf16 v16 = (bf16)acc[mt][nt][r];
                if (mode == 0) {
                    out[(size_t)row * 512 + col] = v16;
                } else {
                    const int bb = row >> 12, c = row & 4095;
                    const int hh = col >> 6,  d = col & 63;
                    out[(size_t)((bb * 8 + hh) * 64 + d) * 4096 + c] = v16;
                }
            }
        }
    }
}

// ---------------------------------------------------------------------------
// Out-proj GEMM: out_f32[8192x512] = Ob_bf16[8192x512] @ wout_f32^T + bout.
// ---------------------------------------------------------------------------
__global__ __launch_bounds__(256, 2) void mm_oproj(
    const bf16* __restrict__ Ob, const float* __restrict__ wout,
    const float* __restrict__ bout, float* __restrict__ out)
{
    __shared__ bf16 Al[128 * 40];
    __shared__ bf16 Wl[128 * 40];

    const int tid  = threadIdx.x;
    const int lane = tid & 63;
    const int w    = tid >> 6;
    const int wr   = w >> 1, wc = w & 1;
    const int bx   = blockIdx.x, by = blockIdx.y;
    const int q    = lane >> 4, m0 = lane & 15;

    f32x4 acc[4][4];
#pragma unroll
    for (int i = 0; i < 4; i++)
#pragma unroll
        for (int j = 0; j < 4; j++)
#pragma unroll
            for (int r = 0; r < 4; r++) acc[i][j][r] = 0.f;

    const int r0 = tid >> 2;
    const int c0 = (tid & 3) * 8;
    const bf16*  Ab = Ob   + (size_t)(by * 128) * 512;
    const float* Wb = wout + (size_t)(bx * 128) * 512;

    for (int k0 = 0; k0 < 512; k0 += 32) {
        *(bf16x8*)&Al[r0 * 40 + c0]        = *(const bf16x8*)(Ab + (size_t)r0 * 512 + k0 + c0);
        *(bf16x8*)&Al[(r0 + 64) * 40 + c0] = *(const bf16x8*)(Ab + (size_t)(r0 + 64) * 512 + k0 + c0);
        *(bf16x8*)&Wl[r0 * 40 + c0]        = ld8_f32_to_bf16(Wb + (size_t)r0 * 512 + k0 + c0);
        *(bf16x8*)&Wl[(r0 + 64) * 40 + c0] = ld8_f32_to_bf16(Wb + (size_t)(r0 + 64) * 512 + k0 + c0);
        __syncthreads();

        bf16x8 af[4], wf[4];
#pragma unroll
        for (int mt = 0; mt < 4; mt++)
            af[mt] = *(const bf16x8*)&Al[(wr * 64 + mt * 16 + m0) * 40 + q * 8];
#pragma unroll
        for (int nt = 0; nt < 4; nt++)
            wf[nt] = *(const bf16x8*)&Wl[(wc * 64 + nt * 16 + m0) * 40 + q * 8];
#pragma unroll
        for (int mt = 0; mt < 4; mt++)
#pragma unroll
            for (int nt = 0; nt < 4; nt++)
                acc[mt][nt] = MFMA16(af[mt], wf[nt], acc[mt][nt]);
        __syncthreads();
    }

#pragma unroll
    for (int nt = 0; nt < 4; nt++) {
        const int col = bx * 128 + wc * 64 + nt * 16 + m0;
        const float bv = bout[col];
#pragma unroll
        for (int mt = 0; mt < 4; mt++) {
#pragma unroll
            for (int r = 0; r < 4; r++) {
                const int row = by * 128 + wr * 64 + mt * 16 + q * 4 + r;
                out[(size_t)row * 512 + col] = acc[mt][nt][r] + bv;
            }
        }
    }
}

// ---------------------------------------------------------------------------
// Flash attention, 16x16x32 MFMA (verified lane-mappings). Wave = 16 q-rows.
// Per 64-c chunk: S = Q.K^T (4 c-tiles x 2 MFMAs over d=64); per-row online
// softmax (in-lane over ct + 16-lane butterfly within quad); P via per-wave
// LDS (barriered); O += P.V with V^T B-frags. f32 softmax state.
// ---------------------------------------------------------------------------
__global__ __launch_bounds__(256, 2) void fa_attn(
    const bf16* __restrict__ Qb, const bf16* __restrict__ Kb,
    const bf16* __restrict__ Vtb, bf16* __restrict__ Ob)
{
    __shared__ bf16 Kl[64 * 72];        // K chunk [c][d]
    __shared__ bf16 Vl[64 * 72];        // V^T chunk [d][c]
    __shared__ bf16 Pw[4][16 * 72];     // per-wave P [s][c]

    const int tid  = threadIdx.x;
    const int lane = tid & 63;
    const int w    = tid >> 6;
    const int q    = lane >> 4;
    const int m0   = lane & 15;
    const int b    = blockIdx.z, h0 = blockIdx.y;
    const int qg   = blockIdx.x * 64 + w * 16;

    bf16x8 af[2];
    const bf16* qp = Qb + (size_t)(b * 4096 + qg + m0) * 512 + h0 * 64 + q * 8;
#pragma unroll
    for (int kd = 0; kd < 2; kd++) {
        bf16x8 t = *(const bf16x8*)(qp + kd * 32);
#pragma unroll
        for (int j = 0; j < 8; j++) t[j] = (bf16)((float)t[j] * 0.125f);  // exact
        af[kd] = t;
    }

    f32x4 oc[4];
#pragma unroll
    for (int dt = 0; dt < 4; dt++)
#pragma unroll
        for (int r = 0; r < 4; r++) oc[dt][r] = 0.f;
    float mrun[4], lrun[4];
#pragma unroll
    for (int r = 0; r < 4; r++) { mrun[r] = -1e30f; lrun[r] = 0.f; }

    const int srow = tid >> 2;
    const int scol = (tid & 3) * 16;
    const bf16* Kg = Kb  + (size_t)(b * 4096) * 512 + h0 * 64;
    const bf16* Vg = Vtb + (size_t)(b * 8 + h0) * 64 * 4096;

    for (int cb = 0; cb < 4096; cb += 64) {
        *(bf16x8*)&Kl[srow * 72 + scol]     = *(const bf16x8*)(Kg + (size_t)(cb + srow) * 512 + scol);
        *(bf16x8*)&Kl[srow * 72 + scol + 8] = *(const bf16x8*)(Kg + (size_t)(cb + srow) * 512 + scol + 8);
        *(bf16x8*)&Vl[srow * 72 + scol]     = *(const bf16x8*)(Vg + (size_t)srow * 4096 + cb + scol);
        *(bf16x8*)&Vl[srow * 72 + scol + 8] = *(const bf16x8*)(Vg + (size_t)srow * 4096 + cb + scol + 8);
        __syncthreads();

        f32x4 st[4];
#pragma unroll
        for (int ct = 0; ct < 4; ct++) {
#pragma unroll
            for (int r = 0; r < 4; r++) st[ct][r] = 0.f;
            bf16x8 k0 = *(const bf16x8*)&Kl[(ct * 16 + m0) * 72 + q * 8];
            bf16x8 k1 = *(const bf16x8*)&Kl[(ct * 16 + m0) * 72 + 32 + q * 8];
            st[ct] = MFMA16(af[0], k0, st[ct]);
            st[ct] = MFMA16(af[1], k1, st[ct]);
        }

        float mx[4];
#pragma unroll
        for (int r = 0; r < 4; r++)
            mx[r] = fmaxf(fmaxf(st[0][r], st[1][r]), fmaxf(st[2][r], st[3][r]));
#pragma unroll
        for (int mask = 1; mask < 16; mask <<= 1)
#pragma unroll
            for (int r = 0; r < 4; r++) mx[r] = fmaxf(mx[r], __shfl_xor(mx[r], mask));

        float al[4];
#pragma unroll
        for (int r = 0; r < 4; r++) {
            const float mnew = fmaxf(mrun[r], mx[r]);
            al[r] = __expf(mrun[r] - mnew);
            mrun[r] = mnew;
        }
        float p[4][4], rs[4];
#pragma unroll
        for (int r = 0; r < 4; r++) rs[r] = 0.f;
#pragma unroll
        for (int ct = 0; ct < 4; ct++)
#pragma unroll
            for (int r = 0; r < 4; r++) {
                p[ct][r] = __expf(st[ct][r] - mrun[r]);
                rs[r] += p[ct][r];
            }
#pragma unroll
        for (int mask = 1; mask < 16; mask <<= 1)
#pragma unroll
            for (int r = 0; r < 4; r++) rs[r] += __shfl_xor(rs[r], mask);
#pragma unroll
        for (int r = 0; r < 4; r++) lrun[r] = lrun[r] * al[r] + rs[r];
#pragma unroll
        for (int dt = 0; dt < 4; dt++)
#pragma unroll
            for (int r = 0; r < 4; r++) oc[dt][r] *= al[r];

#pragma unroll
        for (int ct = 0; ct < 4; ct++)
#pragma unroll
            for (int r = 0; r < 4; r++)
                Pw[w][(q * 4 + r) * 72 + ct * 16 + m0] = (bf16)p[ct][r];
        __syncthreads();

        bf16x8 pf0 = *(const bf16x8*)&Pw[w][m0 * 72 + q * 8];
        bf16x8 pf1 = *(const bf16x8*)&Pw[w][m0 * 72 + 32 + q * 8];
#pragma unroll
        for (int dt = 0; dt < 4; dt++) {
            bf16x8 v0 = *(const bf16x8*)&Vl[(dt * 16 + m0) * 72 + q * 8];
            bf16x8 v1 = *(const bf16x8*)&Vl[(dt * 16 + m0) * 72 + 32 + q * 8];
            oc[dt] = MFMA16(pf0, v0, oc[dt]);
            oc[dt] = MFMA16(pf1, v1, oc[dt]);
        }
        __syncthreads();
    }

    float rli[4];
#pragma unroll
    for (int r = 0; r < 4; r++) rli[r] = 1.0f / lrun[r];
    bf16* ob = Ob + (size_t)(b * 4096 + qg) * 512 + h0 * 64;
#pragma unroll
    for (int dt = 0; dt < 4; dt++)
#pragma unroll
        for (int r = 0; r < 4; r++)
            ob[(size_t)(q * 4 + r) * 512 + dt * 16 + m0] = (bf16)(oc[dt][r] * rli[r]);
}

__global__ void ws_sig11(float* out) { if (threadIdx.x == 0) out[0] = 777.0f; }

// ---------------------------------------------------------------------------
extern "C" void kernel_launch(void* const* d_in, const int* in_sizes, int n_in,
                              void* d_out, int out_size, void* d_ws, size_t ws_size,
                              hipStream_t stream)
{
    const float* x    = (const float*)d_in[0];   // [2,4096,512] f32
    const float* ctx  = (const float*)d_in[1];   // [2,4096,512] f32
    const float* wq   = (const float*)d_in[2];   // [512,512] f32 [out][in]
    const float* wk   = (const float*)d_in[3];
    const float* wv   = (const float*)d_in[4];
    const float* wout = (const float*)d_in[5];
    const float* bout = (const float*)d_in[6];   // [512] f32
    float* out = (float*)d_out;                  // [2,4096,512] f32

    char* ws = (char*)d_ws;
    const size_t MB = 1024 * 1024;
    const size_t SZ = (size_t)8192 * 512 * sizeof(bf16);   // 8 MiB per buffer
    if (ws_size < 32 * MB) {
        ws_sig11<<<dim3(1), dim3(64), 0, stream>>>(out);
        return;
    }

    bf16* Qb  = (bf16*)(ws);            // [B*S, 512]
    bf16* Kb  = (bf16*)(ws + SZ);       // [B*C, 512]
    bf16* Vtb = (bf16*)(ws + 2 * SZ);   // [B,H,64,C] transposed V
    bf16* Ob  = (bf16*)(ws + 3 * SZ);   // [B*S, 512]

    mm_qkv  <<<dim3(4, 64, 3), dim3(256), 0, stream>>>(x, ctx, wq, wk, wv, Qb, Kb, Vtb);
    fa_attn <<<dim3(64, 8, 2), dim3(256), 0, stream>>>(Qb, Kb, Vtb, Ob);
    mm_oproj<<<dim3(4, 64, 1), dim3(256), 0, stream>>>(Ob, wout, bout, out);
}